// Round 5
// baseline (290.330 us; speedup 1.0000x reference)
//
#include <hip/hip_runtime.h>
#include <hip/hip_bf16.h>

#define NB 2
#define NPTS 5000
#define DIM 128
#define KNN 6
#define MEAN_OFF (2*5001*128)

// ---------------- Kernel 1: precompute folded weights + depot rows + mean init
// A  = W_init @ W_final   (3x128)  -> ws[0..383]
// Bm = W_nbr  @ W_final   (3x128)  -> ws[384..767]
// c  = (b_init + 6 b_nbr) @ W_final + 7 b_final (128) -> ws[768..895]
__global__ __launch_bounds__(256) void pre_kernel(
    const float* __restrict__ W_init, const float* __restrict__ b_init,
    const float* __restrict__ W_nbr,  const float* __restrict__ b_nbr,
    const float* __restrict__ W_depot,const float* __restrict__ b_depot,
    const float* __restrict__ W_final,const float* __restrict__ b_final,
    const float* __restrict__ depot,
    float* __restrict__ ws, float* __restrict__ out) {
  const int tid = threadIdx.x;
  for (int idx = tid; idx < 768; idx += 256) {
    const float* Ws = (idx < 384) ? W_init : W_nbr;
    int rem = (idx >= 384) ? idx - 384 : idx;
    int t = rem >> 7, d = rem & 127;
    float acc = 0.f;
    for (int e = 0; e < 128; ++e) acc += Ws[t*128 + e] * W_final[e*128 + d];
    ws[idx] = acc;
  }
  if (tid < 128) {
    float acc = 0.f;
    for (int e = 0; e < 128; ++e) acc += (b_init[e] + 6.f*b_nbr[e]) * W_final[e*128 + tid];
    ws[768 + tid] = acc + 7.f*b_final[tid];
  }
  {
    int b = tid >> 7, d = tid & 127;
    float val = depot[b*2] * W_depot[d] + depot[b*2+1] * W_depot[128 + d] + b_depot[d];
    out[(size_t)b*5001*128 + d] = val;                    // h[b,0,:]
    out[MEAN_OFF + b*128 + d]   = val * (1.f/5001.f);     // mean init (depot term)
  }
}

// ---------------- Kernel 2: 6-NN per point (4 chunk-threads per query + merge)
// Scan keeps f32 dist + i32 idx (cheap chain; strict '<' + monotone j =>
// stable within chunk). Cross-chunk merge uses u64 keys (dist_bits<<32)|j:
// strict u64 '<' == jnp.argsort's stable order exactly.
#define PACK(d_, j_) ((((unsigned long long)__float_as_uint(d_)) << 32) | (unsigned)(j_))
#define INSF(nd, nj) \
  { bool c_; float td_; int tj_; \
    c_ = nd<dl0; td_=dl0; tj_=il0; dl0=c_?nd:dl0; il0=c_?nj:il0; nd=c_?td_:nd; nj=c_?tj_:nj; \
    c_ = nd<dl1; td_=dl1; tj_=il1; dl1=c_?nd:dl1; il1=c_?nj:il1; nd=c_?td_:nd; nj=c_?tj_:nj; \
    c_ = nd<dl2; td_=dl2; tj_=il2; dl2=c_?nd:dl2; il2=c_?nj:il2; nd=c_?td_:nd; nj=c_?tj_:nj; \
    c_ = nd<dl3; td_=dl3; tj_=il3; dl3=c_?nd:dl3; il3=c_?nj:il3; nd=c_?td_:nd; nj=c_?tj_:nj; \
    c_ = nd<dl4; td_=dl4; tj_=il4; dl4=c_?nd:dl4; il4=c_?nj:il4; nd=c_?td_:nd; nj=c_?tj_:nj; \
    c_ = nd<dl5; dl5=c_?nd:dl5; il5=c_?nj:il5; }
#define INS6(nk) \
  { bool c_; unsigned long long t_; \
    c_ = nk<k0; t_=k0; k0=c_?nk:k0; nk=c_?t_:nk; \
    c_ = nk<k1; t_=k1; k1=c_?nk:k1; nk=c_?t_:nk; \
    c_ = nk<k2; t_=k2; k2=c_?nk:k2; nk=c_?t_:nk; \
    c_ = nk<k3; t_=k3; k3=c_?nk:k3; nk=c_?t_:nk; \
    c_ = nk<k4; t_=k4; k4=c_?nk:k4; nk=c_?t_:nk; \
    c_ = nk<k5; k5=c_?nk:k5; }

__global__ __launch_bounds__(256) void knn_kernel(
    const float* __restrict__ loc, const float* __restrict__ deadline,
    float* __restrict__ nbrsum /* = ws + 1024, stride 4 per row */) {
  const int b = blockIdx.y;
  __shared__ float2 sp[NPTS];
  __shared__ unsigned long long cand[64*4*6];
  const float2* locb = (const float2*)(loc + (size_t)b*NPTS*2);
  for (int k = threadIdx.x; k < NPTS; k += 256) sp[k] = locb[k];
  __syncthreads();

  const int q = threadIdx.x & 63;      // query slot in block
  const int c = threadIdx.x >> 6;      // candidate chunk 0..3
  const int i = blockIdx.x*64 + q;     // global query index
  const bool valid = (i < NPTS);

  const float FINF = __builtin_inff();
  float dl0=FINF,dl1=FINF,dl2=FINF,dl3=FINF,dl4=FINF,dl5=FINF;
  int   il0=0,   il1=0,   il2=0,   il3=0,   il4=0,   il5=0;
  if (valid) {
    const float px = sp[i].x, py = sp[i].y;
    float t2m = FINF;                  // conservative squared-dist filter
    const int j0 = c*(NPTS/4), j1 = j0 + (NPTS/4);
    for (int j = j0; j < j1; ++j) {
      float2 p = sp[j];
      float dx = px - p.x, dy = py - p.y;
      float s = dx*dx + dy*dy;         // fast (fma ok), filter only
      if (s < t2m) {
        // precise, separately-rounded distance matching jnp.linalg.norm
        float ss = __fadd_rn(__fmul_rn(dx,dx), __fmul_rn(dy,dy));
        float nd = sqrtf(ss);
        int   nj = j;
        INSF(nd, nj);
        t2m = dl5*dl5*1.000002f;       // margin: no false rejects
      }
    }
  }
  unsigned long long* my = &cand[(unsigned)((q<<2)|c)*6];
  my[0]=PACK(dl0,il0); my[1]=PACK(dl1,il1); my[2]=PACK(dl2,il2);
  my[3]=PACK(dl3,il3); my[4]=PACK(dl4,il4); my[5]=PACK(dl5,il5);
  __syncthreads();

  if (c == 0 && valid) {
    // our own chunk's list, as u64 keys (from registers, no LDS reload)
    unsigned long long k0=PACK(dl0,il0), k1=PACK(dl1,il1), k2=PACK(dl2,il2),
                       k3=PACK(dl3,il3), k4=PACK(dl4,il4), k5=PACK(dl5,il5);
    for (int cc = 1; cc < 4; ++cc) {
      const unsigned long long* o = &cand[(unsigned)((q<<2)|cc)*6];
#pragma unroll
      for (int t = 0; t < 6; ++t) {
        unsigned long long nk = o[t];
        if (nk >= k5) break;           // o[] sorted -> rest can't qualify
        INS6(nk);
      }
    }
    // gather from batch-0 x (the reference's x[0][neighbors] quirk)
    float s0=0.f, s1=0.f, s2=0.f;
    { int j=(int)(unsigned)k0; s0+=loc[j*2]; s1+=loc[j*2+1]; s2+=deadline[j]; }
    { int j=(int)(unsigned)k1; s0+=loc[j*2]; s1+=loc[j*2+1]; s2+=deadline[j]; }
    { int j=(int)(unsigned)k2; s0+=loc[j*2]; s1+=loc[j*2+1]; s2+=deadline[j]; }
    { int j=(int)(unsigned)k3; s0+=loc[j*2]; s1+=loc[j*2+1]; s2+=deadline[j]; }
    { int j=(int)(unsigned)k4; s0+=loc[j*2]; s1+=loc[j*2+1]; s2+=deadline[j]; }
    { int j=(int)(unsigned)k5; s0+=loc[j*2]; s1+=loc[j*2+1]; s2+=deadline[j]; }
    const size_t o = ((size_t)b*NPTS + i) * 4;
    nbrsum[o] = s0; nbrsum[o+1] = s1; nbrsum[o+2] = s2;
  }
}

// ---------------- Kernel 3: h rows + mean accumulation
__global__ __launch_bounds__(256) void rows_kernel(
    const float* __restrict__ loc, const float* __restrict__ deadline,
    const float* __restrict__ ws, float* __restrict__ out) {
  const int b  = blockIdx.y;
  const int d  = threadIdx.x & 127;
  const int rs = threadIdx.x >> 7;
  const float A0 = ws[d],      A1 = ws[128+d], A2 = ws[256+d];
  const float B0 = ws[384+d],  B1 = ws[512+d], B2 = ws[640+d];
  const float cc = ws[768+d];
  const float* __restrict__ nbrsum = ws + 1024;
  float msum = 0.f;
#pragma unroll
  for (int it = 0; it < 8; ++it) {
    int i = blockIdx.x*16 + it*2 + rs;
    if (i < NPTS) {
      size_t r = (size_t)b*NPTS + i;
      float u0 = loc[r*2], u1 = loc[r*2+1], u2 = deadline[r];
      float w0 = nbrsum[r*4]   - 6.f*u0;
      float w1 = nbrsum[r*4+1] - 6.f*u1;
      float w2 = nbrsum[r*4+2] - 6.f*u2;
      float val = cc + u0*A0 + u1*A1 + u2*A2 + w0*B0 + w1*B1 + w2*B2;
      out[((size_t)b*5001 + 1 + i)*128 + d] = val;
      msum += val;
    }
  }
  atomicAdd(&out[MEAN_OFF + b*128 + d], msum * (1.f/5001.f));
}

extern "C" void kernel_launch(void* const* d_in, const int* in_sizes, int n_in,
                              void* d_out, int out_size, void* d_ws, size_t ws_size,
                              hipStream_t stream) {
  const float* loc      = (const float*)d_in[0];
  const float* deadline = (const float*)d_in[1];
  const float* depot    = (const float*)d_in[2];
  const float* W_init   = (const float*)d_in[3];
  const float* b_init   = (const float*)d_in[4];
  const float* W_nbr    = (const float*)d_in[5];
  const float* b_nbr    = (const float*)d_in[6];
  const float* W_depot  = (const float*)d_in[7];
  const float* b_depot  = (const float*)d_in[8];
  const float* W_final  = (const float*)d_in[9];
  const float* b_final  = (const float*)d_in[10];
  float* out = (float*)d_out;
  float* ws  = (float*)d_ws;

  hipLaunchKernelGGL(pre_kernel, dim3(1), dim3(256), 0, stream,
                     W_init, b_init, W_nbr, b_nbr, W_depot, b_depot,
                     W_final, b_final, depot, ws, out);
  hipLaunchKernelGGL(knn_kernel, dim3((NPTS + 63)/64, NB), dim3(256), 0, stream,
                     loc, deadline, ws + 1024);
  hipLaunchKernelGGL(rows_kernel, dim3((NPTS + 15)/16, NB), dim3(256), 0, stream,
                     loc, deadline, ws, out);
}

// Round 6
// 205.081 us; speedup vs baseline: 1.4157x; 1.4157x over previous
//
#include <hip/hip_runtime.h>
#include <hip/hip_bf16.h>

#define NB 2
#define NPTS 5000
#define DIM 128
#define KNN 6
#define NZ 4
#define ZLEN (NPTS/NZ)            /* 1250 */
#define MEAN_OFF (2*5001*128)
/* ws layout (float units): [0..895] folded weights; [1024..41023] nbrsum;
   [41024..] cand region: NB*NPTS*NZ*6 u64 = 1.92 MB */
#define WS_CAND_F 41024

// ---------------- Kernel 1: precompute folded weights + depot rows + mean init
// A  = W_init @ W_final   (3x128)  -> ws[0..383]
// Bm = W_nbr  @ W_final   (3x128)  -> ws[384..767]
// c  = (b_init + 6 b_nbr) @ W_final + 7 b_final (128) -> ws[768..895]
__global__ __launch_bounds__(256) void pre_kernel(
    const float* __restrict__ W_init, const float* __restrict__ b_init,
    const float* __restrict__ W_nbr,  const float* __restrict__ b_nbr,
    const float* __restrict__ W_depot,const float* __restrict__ b_depot,
    const float* __restrict__ W_final,const float* __restrict__ b_final,
    const float* __restrict__ depot,
    float* __restrict__ ws, float* __restrict__ out) {
  const int tid = threadIdx.x;
  for (int idx = tid; idx < 768; idx += 256) {
    const float* Ws = (idx < 384) ? W_init : W_nbr;
    int rem = (idx >= 384) ? idx - 384 : idx;
    int t = rem >> 7, d = rem & 127;
    float acc = 0.f;
    for (int e = 0; e < 128; ++e) acc += Ws[t*128 + e] * W_final[e*128 + d];
    ws[idx] = acc;
  }
  if (tid < 128) {
    float acc = 0.f;
    for (int e = 0; e < 128; ++e) acc += (b_init[e] + 6.f*b_nbr[e]) * W_final[e*128 + tid];
    ws[768 + tid] = acc + 7.f*b_final[tid];
  }
  {
    int b = tid >> 7, d = tid & 127;
    float val = depot[b*2] * W_depot[d] + depot[b*2+1] * W_depot[128 + d] + b_depot[d];
    out[(size_t)b*5001*128 + d] = val;                    // h[b,0,:]
    out[MEAN_OFF + b*128 + d]   = val * (1.f/5001.f);     // mean init (depot term)
  }
}

// Keys pack (dist_bits<<32)|global_j: strict u64 '<' == stable argsort order.
#define PACK(d_, j_) ((((unsigned long long)__float_as_uint(d_)) << 32) | (unsigned)(j_))
#define INSF(nd, nj) \
  { bool c_; float td_; int tj_; \
    c_ = nd<dl0; td_=dl0; tj_=il0; dl0=c_?nd:dl0; il0=c_?nj:il0; nd=c_?td_:nd; nj=c_?tj_:nj; \
    c_ = nd<dl1; td_=dl1; tj_=il1; dl1=c_?nd:dl1; il1=c_?nj:il1; nd=c_?td_:nd; nj=c_?tj_:nj; \
    c_ = nd<dl2; td_=dl2; tj_=il2; dl2=c_?nd:dl2; il2=c_?nj:il2; nd=c_?td_:nd; nj=c_?tj_:nj; \
    c_ = nd<dl3; td_=dl3; tj_=il3; dl3=c_?nd:dl3; il3=c_?nj:il3; nd=c_?td_:nd; nj=c_?tj_:nj; \
    c_ = nd<dl4; td_=dl4; tj_=il4; dl4=c_?nd:dl4; il4=c_?nj:il4; nd=c_?td_:nd; nj=c_?tj_:nj; \
    c_ = nd<dl5; dl5=c_?nd:dl5; il5=c_?nj:il5; }
#define INS6(nk) \
  { bool c_; unsigned long long t_; \
    c_ = nk<k0; t_=k0; k0=c_?nk:k0; nk=c_?t_:nk; \
    c_ = nk<k1; t_=k1; k1=c_?nk:k1; nk=c_?t_:nk; \
    c_ = nk<k2; t_=k2; k2=c_?nk:k2; nk=c_?t_:nk; \
    c_ = nk<k3; t_=k3; k3=c_?nk:k3; nk=c_?t_:nk; \
    c_ = nk<k4; t_=k4; k4=c_?nk:k4; nk=c_?t_:nk; \
    c_ = nk<k5; k5=c_?nk:k5; }

// ---------------- Kernel 2: partial 6-NN over one z-chunk of 1250 candidates.
// Block = 64 queries x 4 chunk-threads; per-thread scan ~313 candidates.
// Grid (79, NB, NZ) = 632 blocks -> ~31% occupancy (vs 6.6% monolithic).
__global__ __launch_bounds__(256) void knn_part(
    const float* __restrict__ loc,
    unsigned long long* __restrict__ cand /* [(b*NPTS+i)*NZ+z]*6 */) {
  const int b = blockIdx.y, z = blockIdx.z;
  const int zbase = z*ZLEN;
  __shared__ float2 sp[ZLEN];
  __shared__ unsigned long long lmerge[64*4*6];
  const float2* locb = (const float2*)(loc + (size_t)b*NPTS*2);
  for (int k = threadIdx.x; k < ZLEN; k += 256) sp[k] = locb[zbase + k];
  __syncthreads();

  const int q = threadIdx.x & 63;      // query slot in block
  const int c = threadIdx.x >> 6;      // candidate sub-chunk 0..3
  const int i = blockIdx.x*64 + q;     // global query index
  const bool valid = (i < NPTS);

  const float FINF = __builtin_inff();
  float dl0=FINF,dl1=FINF,dl2=FINF,dl3=FINF,dl4=FINF,dl5=FINF;
  int   il0=0,   il1=0,   il2=0,   il3=0,   il4=0,   il5=0;
  if (valid) {
    const float2 qp = locb[i];         // coalesced 8B/lane global read
    const float px = qp.x, py = qp.y;
    float t2m = FINF;                  // conservative squared-dist filter
    const int j0 = (c*ZLEN)/4, j1 = ((c+1)*ZLEN)/4;
#pragma unroll 4
    for (int j = j0; j < j1; ++j) {
      float2 p = sp[j];
      float dx = px - p.x, dy = py - p.y;
      float s = dx*dx + dy*dy;         // fast (fma ok), filter only
      if (s < t2m) {
        // precise, separately-rounded distance matching jnp.linalg.norm
        float ss = __fadd_rn(__fmul_rn(dx,dx), __fmul_rn(dy,dy));
        float nd = sqrtf(ss);
        int   nj = zbase + j;          // GLOBAL candidate index
        INSF(nd, nj);
        t2m = dl5*dl5*1.000002f;       // margin: no false rejects
      }
    }
  }
  unsigned long long* my = &lmerge[(unsigned)((q<<2)|c)*6];
  my[0]=PACK(dl0,il0); my[1]=PACK(dl1,il1); my[2]=PACK(dl2,il2);
  my[3]=PACK(dl3,il3); my[4]=PACK(dl4,il4); my[5]=PACK(dl5,il5);
  __syncthreads();

  if (c == 0 && valid) {
    unsigned long long k0=PACK(dl0,il0), k1=PACK(dl1,il1), k2=PACK(dl2,il2),
                       k3=PACK(dl3,il3), k4=PACK(dl4,il4), k5=PACK(dl5,il5);
    for (int cc = 1; cc < 4; ++cc) {
      const unsigned long long* o = &lmerge[(unsigned)((q<<2)|cc)*6];
#pragma unroll
      for (int t = 0; t < 6; ++t) {
        unsigned long long nk = o[t];
        if (nk >= k5) break;           // o[] sorted -> rest can't qualify
        INS6(nk);
      }
    }
    unsigned long long* dst = &cand[((size_t)((size_t)b*NPTS + i)*NZ + z)*6];
    dst[0]=k0; dst[1]=k1; dst[2]=k2; dst[3]=k3; dst[4]=k4; dst[5]=k5;
  }
}

// ---------------- Kernel 3: merge NZ partial lists -> final top-6, gather
// from batch-0 x (the reference's x[0][neighbors] quirk), emit nbrsum.
__global__ __launch_bounds__(256) void merge_final(
    const float* __restrict__ loc, const float* __restrict__ deadline,
    const unsigned long long* __restrict__ cand,
    float* __restrict__ nbrsum /* stride 4 per row */) {
  const int idx = blockIdx.x*256 + threadIdx.x;   // over NB*NPTS
  if (idx >= NB*NPTS) return;
  const unsigned long long* src = &cand[(size_t)idx*NZ*6];
  unsigned long long k0=src[0],k1=src[1],k2=src[2],k3=src[3],k4=src[4],k5=src[5];
  for (int z = 1; z < NZ; ++z) {
    const unsigned long long* o = &src[z*6];
#pragma unroll
    for (int t = 0; t < 6; ++t) {
      unsigned long long nk = o[t];
      if (nk >= k5) break;             // sorted -> rest can't qualify
      INS6(nk);
    }
  }
  float s0=0.f, s1=0.f, s2=0.f;
  { int j=(int)(unsigned)k0; s0+=loc[j*2]; s1+=loc[j*2+1]; s2+=deadline[j]; }
  { int j=(int)(unsigned)k1; s0+=loc[j*2]; s1+=loc[j*2+1]; s2+=deadline[j]; }
  { int j=(int)(unsigned)k2; s0+=loc[j*2]; s1+=loc[j*2+1]; s2+=deadline[j]; }
  { int j=(int)(unsigned)k3; s0+=loc[j*2]; s1+=loc[j*2+1]; s2+=deadline[j]; }
  { int j=(int)(unsigned)k4; s0+=loc[j*2]; s1+=loc[j*2+1]; s2+=deadline[j]; }
  { int j=(int)(unsigned)k5; s0+=loc[j*2]; s1+=loc[j*2+1]; s2+=deadline[j]; }
  const size_t o = (size_t)idx * 4;
  nbrsum[o] = s0; nbrsum[o+1] = s1; nbrsum[o+2] = s2;
}

// ---------------- Kernel 4: h rows + mean accumulation
__global__ __launch_bounds__(256) void rows_kernel(
    const float* __restrict__ loc, const float* __restrict__ deadline,
    const float* __restrict__ ws, float* __restrict__ out) {
  const int b  = blockIdx.y;
  const int d  = threadIdx.x & 127;
  const int rs = threadIdx.x >> 7;
  const float A0 = ws[d],      A1 = ws[128+d], A2 = ws[256+d];
  const float B0 = ws[384+d],  B1 = ws[512+d], B2 = ws[640+d];
  const float cc = ws[768+d];
  const float* __restrict__ nbrsum = ws + 1024;
  float msum = 0.f;
#pragma unroll
  for (int it = 0; it < 8; ++it) {
    int i = blockIdx.x*16 + it*2 + rs;
    if (i < NPTS) {
      size_t r = (size_t)b*NPTS + i;
      float u0 = loc[r*2], u1 = loc[r*2+1], u2 = deadline[r];
      float w0 = nbrsum[r*4]   - 6.f*u0;
      float w1 = nbrsum[r*4+1] - 6.f*u1;
      float w2 = nbrsum[r*4+2] - 6.f*u2;
      float val = cc + u0*A0 + u1*A1 + u2*A2 + w0*B0 + w1*B1 + w2*B2;
      out[((size_t)b*5001 + 1 + i)*128 + d] = val;
      msum += val;
    }
  }
  atomicAdd(&out[MEAN_OFF + b*128 + d], msum * (1.f/5001.f));
}

extern "C" void kernel_launch(void* const* d_in, const int* in_sizes, int n_in,
                              void* d_out, int out_size, void* d_ws, size_t ws_size,
                              hipStream_t stream) {
  const float* loc      = (const float*)d_in[0];
  const float* deadline = (const float*)d_in[1];
  const float* depot    = (const float*)d_in[2];
  const float* W_init   = (const float*)d_in[3];
  const float* b_init   = (const float*)d_in[4];
  const float* W_nbr    = (const float*)d_in[5];
  const float* b_nbr    = (const float*)d_in[6];
  const float* W_depot  = (const float*)d_in[7];
  const float* b_depot  = (const float*)d_in[8];
  const float* W_final  = (const float*)d_in[9];
  const float* b_final  = (const float*)d_in[10];
  float* out = (float*)d_out;
  float* ws  = (float*)d_ws;
  unsigned long long* cand = (unsigned long long*)(ws + WS_CAND_F);

  hipLaunchKernelGGL(pre_kernel, dim3(1), dim3(256), 0, stream,
                     W_init, b_init, W_nbr, b_nbr, W_depot, b_depot,
                     W_final, b_final, depot, ws, out);
  hipLaunchKernelGGL(knn_part, dim3((NPTS + 63)/64, NB, NZ), dim3(256), 0, stream,
                     loc, cand);
  hipLaunchKernelGGL(merge_final, dim3((NB*NPTS + 255)/256), dim3(256), 0, stream,
                     loc, deadline, cand, ws + 1024);
  hipLaunchKernelGGL(rows_kernel, dim3((NPTS + 15)/16, NB), dim3(256), 0, stream,
                     loc, deadline, ws, out);
}

// Round 9
// 159.222 us; speedup vs baseline: 1.8234x; 1.2880x over previous
//
#include <hip/hip_runtime.h>
#include <hip/hip_bf16.h>

#define NB 2
#define NPTS 5000
#define DIM 128
#define G 64
#define NCELL (G*G)
#define HCELL (1.0f/G)
#define MEAN_OFF (2*5001*128)

/* ws float layout:
   [0..895]      folded weights A(3x128), Bm(3x128), c(128)
   [1024..41023] nbrsum: 10000 rows x 4 floats
   int region at float offset WS_INT_F:
     cellStart: NB*(NCELL+1)   (flat exclusive prefix + total sentinel)
     cursor:    NB*NCELL       (counts, then scatter cursors)
     ptsJ:      NB*NPTS        (original index of sorted point)
   float2 region at WS_XY_F (even => 8B aligned): ptsXY NB*NPTS           */
#define WS_INT_F 41024
#define OFF_CSTART 0
#define OFF_CURSOR (NB*(NCELL+1))
#define OFF_PTSJ   (OFF_CURSOR + NB*NCELL)
#define N_INTS     (OFF_PTSJ + NB*NPTS)
#define WS_XY_F    (WS_INT_F + N_INTS)   /* 67410, even */

// ---------------- Kernel 1: folded weights + depot rows + mean init + zero counters
__global__ __launch_bounds__(256) void pre_kernel(
    const float* __restrict__ W_init, const float* __restrict__ b_init,
    const float* __restrict__ W_nbr,  const float* __restrict__ b_nbr,
    const float* __restrict__ W_depot,const float* __restrict__ b_depot,
    const float* __restrict__ W_final,const float* __restrict__ b_final,
    const float* __restrict__ depot,
    float* __restrict__ ws, float* __restrict__ out) {
  const int tid = threadIdx.x;
  int* __restrict__ cz = (int*)(ws + WS_INT_F) + OFF_CURSOR;
  for (int idx = tid; idx < NB*NCELL; idx += 256) cz[idx] = 0;
  for (int idx = tid; idx < 768; idx += 256) {
    const float* Ws = (idx < 384) ? W_init : W_nbr;
    int rem = (idx >= 384) ? idx - 384 : idx;
    int t = rem >> 7, d = rem & 127;
    float acc = 0.f;
#pragma unroll 8
    for (int e = 0; e < 128; ++e) acc += Ws[t*128 + e] * W_final[e*128 + d];
    ws[idx] = acc;
  }
  if (tid < 128) {
    float acc = 0.f;
#pragma unroll 8
    for (int e = 0; e < 128; ++e) acc += (b_init[e] + 6.f*b_nbr[e]) * W_final[e*128 + tid];
    ws[768 + tid] = acc + 7.f*b_final[tid];
  }
  {
    int b = tid >> 7, d = tid & 127;
    float val = depot[b*2] * W_depot[d] + depot[b*2+1] * W_depot[128 + d] + b_depot[d];
    out[(size_t)b*5001*128 + d] = val;                    // h[b,0,:]
    out[MEAN_OFF + b*128 + d]   = val * (1.f/5001.f);     // mean init (depot term)
  }
}

__device__ __forceinline__ int cell_of(float v) {
  int c = (int)(v * (float)G);
  return c < 0 ? 0 : (c > G-1 ? G-1 : c);
}

// ---------------- Kernel 2: per-cell counts (into cursor)
__global__ __launch_bounds__(256) void count_kernel(
    const float* __restrict__ loc, int* __restrict__ ints) {
  int tid = blockIdx.x*256 + threadIdx.x;
  if (tid >= NB*NPTS) return;
  int b = tid >= NPTS;
  float2 p = ((const float2*)loc)[tid];
  int c = cell_of(p.y)*G + cell_of(p.x);
  atomicAdd(&ints[OFF_CURSOR + b*NCELL + c], 1);
}

// ---------------- Kernel 3: exclusive prefix scan per batch; cursor := start
__global__ __launch_bounds__(1024) void scan_kernel(int* __restrict__ ints) {
  const int b = blockIdx.x, t = threadIdx.x;
  __shared__ int part[1024];
  int* cnt = ints + OFF_CURSOR + b*NCELL;
  int* cst = ints + OFF_CSTART + b*(NCELL+1);
  int c0 = cnt[4*t], c1 = cnt[4*t+1], c2 = cnt[4*t+2], c3 = cnt[4*t+3];
  int tot = c0+c1+c2+c3;
  part[t] = tot;
  __syncthreads();
  for (int off = 1; off < 1024; off <<= 1) {
    int v = (t >= off) ? part[t-off] : 0;
    __syncthreads();
    part[t] += v;
    __syncthreads();
  }
  int base = part[t] - tot;              // exclusive prefix of this thread
  cst[4*t]   = base;            cnt[4*t]   = base;
  cst[4*t+1] = base+c0;         cnt[4*t+1] = base+c0;
  cst[4*t+2] = base+c0+c1;      cnt[4*t+2] = base+c0+c1;
  cst[4*t+3] = base+c0+c1+c2;   cnt[4*t+3] = base+c0+c1+c2;
  if (t == 1023) cst[NCELL] = part[1023];
}

// ---------------- Kernel 4: scatter points into cell-sorted order
__global__ __launch_bounds__(256) void scatter_kernel(
    const float* __restrict__ loc, int* __restrict__ ints,
    float2* __restrict__ xy) {
  int tid = blockIdx.x*256 + threadIdx.x;
  if (tid >= NB*NPTS) return;
  int b = tid >= NPTS;
  int i = tid - b*NPTS;
  float2 p = ((const float2*)loc)[tid];
  int c = cell_of(p.y)*G + cell_of(p.x);
  int pos = atomicAdd(&ints[OFF_CURSOR + b*NCELL + c], 1);
  xy[b*NPTS + pos] = p;
  ints[OFF_PTSJ + b*NPTS + pos] = i;
}

// Keys pack (dist_bits<<32)|global_j: strict u64 '<' == stable argsort order.
#define PACK(d_, j_) ((((unsigned long long)__float_as_uint(d_)) << 32) | (unsigned)(j_))
#define KINIT 0x7f800000ffffffffULL
#define INS6(nk) \
  { bool c_; unsigned long long t_; \
    c_ = nk<k0; t_=k0; k0=c_?nk:k0; nk=c_?t_:nk; \
    c_ = nk<k1; t_=k1; k1=c_?nk:k1; nk=c_?t_:nk; \
    c_ = nk<k2; t_=k2; k2=c_?nk:k2; nk=c_?t_:nk; \
    c_ = nk<k3; t_=k3; k3=c_?nk:k3; nk=c_?t_:nk; \
    c_ = nk<k4; t_=k4; k4=c_?nk:k4; nk=c_?t_:nk; \
    c_ = nk<k5; k5=c_?nk:k5; }

// ---------------- Kernel 5: grid 6-NN + batch-0 gather -> nbrsum
__global__ __launch_bounds__(256) void knn_grid(
    const float* __restrict__ loc, const float* __restrict__ deadline,
    const int* __restrict__ ints, const float2* __restrict__ xy,
    float* __restrict__ nbrsum) {
  const int b = blockIdx.y;
  const int s = blockIdx.x*256 + threadIdx.x;   // sorted slot
  if (s >= NPTS) return;
  const float2* XY = xy + b*NPTS;
  const int*    J  = ints + OFF_PTSJ + b*NPTS;
  const int*    cs = ints + OFF_CSTART + b*(NCELL+1);

  const float2 q = XY[s];
  const int qi = J[s];
  const int cx = cell_of(q.x), cy = cell_of(q.y);

  unsigned long long k0=KINIT,k1=KINIT,k2=KINIT,k3=KINIT,k4=KINIT,k5=KINIT;

#define SCAN_CELL(cidx) \
  { int p0 = cs[cidx], p1 = cs[(cidx)+1]; \
    for (int p = p0; p < p1; ++p) { \
      float2 t = XY[p]; \
      float dx = q.x - t.x, dy = q.y - t.y; \
      float ss = __fadd_rn(__fmul_rn(dx,dx), __fmul_rn(dy,dy)); \
      float nd = sqrtf(ss); \
      unsigned long long nk = PACK(nd, (unsigned)J[p]); \
      if (nk < k5) { INS6(nk); } } }

  // box radius 2 (clipped)
  {
    int x0 = cx-2 < 0 ? 0 : cx-2, x1 = cx+2 > G-1 ? G-1 : cx+2;
    int y0 = cy-2 < 0 ? 0 : cy-2, y1 = cy+2 > G-1 ? G-1 : cy+2;
    for (int y = y0; y <= y1; ++y)
      for (int x = x0; x <= x1; ++x) SCAN_CELL(y*G + x);
  }
  // ring expansion until provably done:
  // all unscanned cells are >= Rb+1 Chebyshev rings away => true dist > Rb*HCELL
  int Rb = 2;
  while (true) {
    float d6 = __uint_as_float((unsigned)(k5 >> 32));
    if (0.999999f * ((float)Rb * HCELL) > d6) break;
    ++Rb;
    if (Rb > G) break;                  // whole grid scanned by now
    int xa = cx-Rb < 0 ? 0 : cx-Rb, xb = cx+Rb > G-1 ? G-1 : cx+Rb;
    int yt = cy-Rb, yb = cy+Rb;
    if (yt >= 0)   { for (int x = xa; x <= xb; ++x) SCAN_CELL(yt*G + x); }
    if (yb <= G-1) { for (int x = xa; x <= xb; ++x) SCAN_CELL(yb*G + x); }
    int ya = cy-Rb+1 < 0 ? 0 : cy-Rb+1, yz = cy+Rb-1 > G-1 ? G-1 : cy+Rb-1;
    if (cx-Rb >= 0)   { for (int y = ya; y <= yz; ++y) SCAN_CELL(y*G + (cx-Rb)); }
    if (cx+Rb <= G-1) { for (int y = ya; y <= yz; ++y) SCAN_CELL(y*G + (cx+Rb)); }
  }

  // gather from batch-0 x (the reference's x[0][neighbors] quirk)
  float s0=0.f, s1=0.f, s2=0.f;
  { int j=(int)(unsigned)k0; s0+=loc[j*2]; s1+=loc[j*2+1]; s2+=deadline[j]; }
  { int j=(int)(unsigned)k1; s0+=loc[j*2]; s1+=loc[j*2+1]; s2+=deadline[j]; }
  { int j=(int)(unsigned)k2; s0+=loc[j*2]; s1+=loc[j*2+1]; s2+=deadline[j]; }
  { int j=(int)(unsigned)k3; s0+=loc[j*2]; s1+=loc[j*2+1]; s2+=deadline[j]; }
  { int j=(int)(unsigned)k4; s0+=loc[j*2]; s1+=loc[j*2+1]; s2+=deadline[j]; }
  { int j=(int)(unsigned)k5; s0+=loc[j*2]; s1+=loc[j*2+1]; s2+=deadline[j]; }
  const size_t o = ((size_t)b*NPTS + qi) * 4;   // ORIGINAL row index
  nbrsum[o] = s0; nbrsum[o+1] = s1; nbrsum[o+2] = s2;
}

// ---------------- Kernel 6: h rows + mean accumulation
__global__ __launch_bounds__(256) void rows_kernel(
    const float* __restrict__ loc, const float* __restrict__ deadline,
    const float* __restrict__ ws, float* __restrict__ out) {
  const int b  = blockIdx.y;
  const int d  = threadIdx.x & 127;
  const int rs = threadIdx.x >> 7;
  const float A0 = ws[d],      A1 = ws[128+d], A2 = ws[256+d];
  const float B0 = ws[384+d],  B1 = ws[512+d], B2 = ws[640+d];
  const float cc = ws[768+d];
  const float* __restrict__ nbrsum = ws + 1024;
  float msum = 0.f;
#pragma unroll
  for (int it = 0; it < 8; ++it) {
    int i = blockIdx.x*16 + it*2 + rs;
    if (i < NPTS) {
      size_t r = (size_t)b*NPTS + i;
      float u0 = loc[r*2], u1 = loc[r*2+1], u2 = deadline[r];
      float w0 = nbrsum[r*4]   - 6.f*u0;
      float w1 = nbrsum[r*4+1] - 6.f*u1;
      float w2 = nbrsum[r*4+2] - 6.f*u2;
      float val = cc + u0*A0 + u1*A1 + u2*A2 + w0*B0 + w1*B1 + w2*B2;
      out[((size_t)b*5001 + 1 + i)*128 + d] = val;
      msum += val;
    }
  }
  atomicAdd(&out[MEAN_OFF + b*128 + d], msum * (1.f/5001.f));
}

extern "C" void kernel_launch(void* const* d_in, const int* in_sizes, int n_in,
                              void* d_out, int out_size, void* d_ws, size_t ws_size,
                              hipStream_t stream) {
  const float* loc      = (const float*)d_in[0];
  const float* deadline = (const float*)d_in[1];
  const float* depot    = (const float*)d_in[2];
  const float* W_init   = (const float*)d_in[3];
  const float* b_init   = (const float*)d_in[4];
  const float* W_nbr    = (const float*)d_in[5];
  const float* b_nbr    = (const float*)d_in[6];
  const float* W_depot  = (const float*)d_in[7];
  const float* b_depot  = (const float*)d_in[8];
  const float* W_final  = (const float*)d_in[9];
  const float* b_final  = (const float*)d_in[10];
  float* out = (float*)d_out;
  float* ws  = (float*)d_ws;
  int*    ints = (int*)(ws + WS_INT_F);
  float2* xy   = (float2*)(ws + WS_XY_F);

  hipLaunchKernelGGL(pre_kernel, dim3(1), dim3(256), 0, stream,
                     W_init, b_init, W_nbr, b_nbr, W_depot, b_depot,
                     W_final, b_final, depot, ws, out);
  hipLaunchKernelGGL(count_kernel, dim3((NB*NPTS + 255)/256), dim3(256), 0, stream,
                     loc, ints);
  hipLaunchKernelGGL(scan_kernel, dim3(NB), dim3(1024), 0, stream, ints);
  hipLaunchKernelGGL(scatter_kernel, dim3((NB*NPTS + 255)/256), dim3(256), 0, stream,
                     loc, ints, xy);
  hipLaunchKernelGGL(knn_grid, dim3((NPTS + 255)/256, NB), dim3(256), 0, stream,
                     loc, deadline, ints, xy, ws + 1024);
  hipLaunchKernelGGL(rows_kernel, dim3((NPTS + 15)/16, NB), dim3(256), 0, stream,
                     loc, deadline, ws, out);
}